// Round 6
// baseline (304.662 us; speedup 1.0000x reference)
//
#include <hip/hip_runtime.h>
#include <hip/hip_bf16.h>

typedef __attribute__((ext_vector_type(8))) short short8;
typedef __attribute__((ext_vector_type(4))) short short4v;
typedef __attribute__((ext_vector_type(4))) float floatx4;
typedef __attribute__((ext_vector_type(2))) float floatx2;
typedef __attribute__((ext_vector_type(16))) float floatx16;

#define B_ 4
#define T_ 2048
#define C_ 1024
#define H_ 16
#define DK_ 64
#define M_ (B_ * T_)   // 8192
#define N3_ (3 * C_)   // 3072

// scale(1/8) * log2(e): folds softmax scaling AND exp->exp2 conversion into Q
#define QSCALE 0.1803368801111243f

__device__ __forceinline__ unsigned short f2bf(float f) {
    union { float f; unsigned u; } v; v.f = f;
    unsigned r = v.u + 0x7fffu + ((v.u >> 16) & 1u);
    return (unsigned short)(r >> 16);
}
__device__ __forceinline__ unsigned fbits(float f) {
    union { float f; unsigned u; } v; v.f = f; return v.u;
}
// pack two f32 -> dword of two bf16 (lo = a, hi = b)
__device__ __forceinline__ unsigned pack_bf16(float a, float b) {
#if __has_builtin(__builtin_amdgcn_cvt_pk_bf16_f32)
    typedef __attribute__((ext_vector_type(2))) __bf16 bf16x2;
    bf16x2 r = __builtin_amdgcn_cvt_pk_bf16_f32(a, b);
    union { bf16x2 v; unsigned u; } c; c.v = r; return c.u;
#else
    return __builtin_amdgcn_perm(fbits(b) + 0x8000u, fbits(a) + 0x8000u, 0x07060302u);
#endif
}

__device__ __forceinline__ void gload_lds16(const unsigned short* g, unsigned short* l) {
    __builtin_amdgcn_global_load_lds(
        (const __attribute__((address_space(1))) unsigned int*)(const void*)g,
        (__attribute__((address_space(3))) unsigned int*)(void*)l, 16, 0, 0);
}

// ---------------- fused cast fp32 -> bf16 for x, w_attn, w_proj --------------
#define NX4 (M_ * C_ / 4)     // 2097152
#define NA4 (N3_ * C_ / 4)    //  786432
#define NP4 (C_ * C_ / 4)     //  262144
__global__ __launch_bounds__(256) void cast3_kernel(const float* __restrict__ x,
                                                    const float* __restrict__ wa,
                                                    const float* __restrict__ wp,
                                                    unsigned short* __restrict__ xb,
                                                    unsigned short* __restrict__ wab,
                                                    unsigned short* __restrict__ wpb) {
    int i = blockIdx.x * 256 + threadIdx.x;
    const float* src; unsigned short* dst; int j;
    if (i < NX4) { src = x; dst = xb; j = i; }
    else if (i < NX4 + NA4) { src = wa; dst = wab; j = i - NX4; }
    else { src = wp; dst = wpb; j = i - NX4 - NA4; }
    float4 v = ((const float4*)src)[j];
    ushort4 o;
    o.x = f2bf(v.x); o.y = f2bf(v.y); o.z = f2bf(v.z); o.w = f2bf(v.w);
    ((ushort4*)dst)[j] = o;
}

// ---------------- B^T GEMM: out[m,n] = sum_k A[m,k]*W[n,k], BK=64 ------------
#define BM 128
#define BN 128
#define BK 64

__global__ __launch_bounds__(256) void gemm_qkv(const unsigned short* __restrict__ A,
                                                const unsigned short* __restrict__ W,
                                                const float* __restrict__ bias,
                                                unsigned short* __restrict__ qout,
                                                unsigned short* __restrict__ kout,
                                                unsigned short* __restrict__ vout) {
    const int Kd = C_;
    __shared__ unsigned short As[BM * BK];
    __shared__ unsigned short Bs[BN * BK];
    int m0 = blockIdx.y * BM;
    int n0 = blockIdx.x * BN;
    int tid = threadIdx.x;
    int lane = tid & 63, w = tid >> 6;
    int wm = (w >> 1) * 64, wn = (w & 1) * 64;
    int l16 = lane & 15, quad = lane >> 4;
    int r8g = lane >> 3, c8g = (lane & 7) * 8;   // staging: 8 rows x 8 chunks

    floatx4 acc[4][4] = {};
    for (int kt = 0; kt < Kd; kt += BK) {
        __syncthreads();
        for (int t = 0; t < 4; ++t) {
            int rbase = w * 32 + t * 8;
            gload_lds16(&A[(size_t)(m0 + rbase + r8g) * Kd + kt + c8g], &As[rbase * BK]);
            gload_lds16(&W[(size_t)(n0 + rbase + r8g) * Kd + kt + c8g], &Bs[rbase * BK]);
        }
        __syncthreads();
        for (int ks = 0; ks < 2; ++ks) {
            short8 af[4], bf[4];
            for (int i = 0; i < 4; ++i)
                af[i] = *(const short8*)&As[(wm + 16 * i + l16) * BK + ks * 32 + quad * 8];
            for (int j = 0; j < 4; ++j)
                bf[j] = *(const short8*)&Bs[(wn + 16 * j + l16) * BK + ks * 32 + quad * 8];
            for (int i = 0; i < 4; ++i)
                for (int j = 0; j < 4; ++j)
                    acc[i][j] = __builtin_amdgcn_mfma_f32_16x16x32_bf16(af[i], bf[j], acc[i][j], 0, 0, 0);
        }
    }
    for (int i = 0; i < 4; ++i)
        for (int j = 0; j < 4; ++j) {
            int col = n0 + wn + 16 * j + l16;
            float bval = bias[col];
            int sec = col >> 10, cc = col & 1023;
            int h = cc >> 6, d = cc & 63;
            float qs = (sec == 0) ? QSCALE : 1.0f;
            unsigned short* dst = (sec == 0) ? qout : ((sec == 1) ? kout : vout);
            for (int r = 0; r < 4; ++r) {
                int m = m0 + wm + 16 * i + quad * 4 + r;
                int b = m >> 11, t = m & (T_ - 1);
                int bh = b * H_ + h;
                dst[((size_t)bh * T_ + t) * DK_ + d] = f2bf((acc[i][j][r] + bval) * qs);
            }
        }
}

__global__ __launch_bounds__(256) void gemm_proj(const unsigned short* __restrict__ A,
                                                 const unsigned short* __restrict__ W,
                                                 const float* __restrict__ bias,
                                                 float* __restrict__ out) {
    const int Kd = C_;
    __shared__ unsigned short As[BM * BK];
    __shared__ unsigned short Bs[BN * BK];
    int m0 = blockIdx.y * BM;
    int n0 = blockIdx.x * BN;
    int tid = threadIdx.x;
    int lane = tid & 63, w = tid >> 6;
    int wm = (w >> 1) * 64, wn = (w & 1) * 64;
    int l16 = lane & 15, quad = lane >> 4;
    int r8g = lane >> 3, c8g = (lane & 7) * 8;

    floatx4 acc[4][4] = {};
    for (int kt = 0; kt < Kd; kt += BK) {
        __syncthreads();
        for (int t = 0; t < 4; ++t) {
            int rbase = w * 32 + t * 8;
            gload_lds16(&A[(size_t)(m0 + rbase + r8g) * Kd + kt + c8g], &As[rbase * BK]);
            gload_lds16(&W[(size_t)(n0 + rbase + r8g) * Kd + kt + c8g], &Bs[rbase * BK]);
        }
        __syncthreads();
        for (int ks = 0; ks < 2; ++ks) {
            short8 af[4], bf[4];
            for (int i = 0; i < 4; ++i)
                af[i] = *(const short8*)&As[(wm + 16 * i + l16) * BK + ks * 32 + quad * 8];
            for (int j = 0; j < 4; ++j)
                bf[j] = *(const short8*)&Bs[(wn + 16 * j + l16) * BK + ks * 32 + quad * 8];
            for (int i = 0; i < 4; ++i)
                for (int j = 0; j < 4; ++j)
                    acc[i][j] = __builtin_amdgcn_mfma_f32_16x16x32_bf16(af[i], bf[j], acc[i][j], 0, 0, 0);
        }
    }
    for (int i = 0; i < 4; ++i)
        for (int j = 0; j < 4; ++j) {
            int col = n0 + wn + 16 * j + l16;
            float bval = bias[col];
            for (int r = 0; r < 4; ++r) {
                int m = m0 + wm + 16 * i + quad * 4 + r;
                out[(size_t)m * C_ + col] = acc[i][j][r] + bval;
            }
        }
}

// ---------------- V transpose + key-permute: [bh,t,d] -> [bh,d,t_perm] -------
// Within each 16-key group, stored order is [0-3, 8-11, 4-7, 12-15]
// (p = (k&3)|((k&8)>>1)|((k&4)<<1)), so the attention PV A-fragment
// (keys {16c+4h..+3} u {16c+8+4h..+3}) is ONE contiguous b128 in LDS.
#define TLD 264
__global__ __launch_bounds__(256) void vtrans_kernel(const unsigned short* __restrict__ V,
                                                     unsigned short* __restrict__ Vt) {
    __shared__ unsigned short L[64 * TLD];
    int bid = blockIdx.x;
    int t0 = (bid & 7) * 256;
    int bh = bid >> 3;
    int tid = threadIdx.x;
    const unsigned short* src = V + ((size_t)bh * T_ + t0) * DK_;
    unsigned short* dst = Vt + (size_t)bh * DK_ * T_ + t0;
    for (int it = 0; it < 8; ++it) {
        int t = it * 32 + (tid >> 3);
        int dseg = (tid & 7) * 8;
        short8 v = *(const short8*)&src[(size_t)t * DK_ + dseg];
        for (int j = 0; j < 8; ++j)
            L[(dseg + j) * TLD + t] = ((unsigned short*)&v)[j];
    }
    __syncthreads();
    for (int it = 0; it < 8; ++it) {
        int d = it * 8 + (tid >> 5);
        int toff = (tid & 31) * 8;
        int g = toff >> 4, s = (toff >> 3) & 1;
        // stored block 8s..8s+7 of group g <- keys {16g+4s..+3, 16g+8+4s..+3}
        short4v lo = *(const short4v*)&L[d * TLD + 16 * g + 4 * s];
        short4v hi = *(const short4v*)&L[d * TLD + 16 * g + 8 + 4 * s];
        short8 r;
        for (int j = 0; j < 4; ++j) { r[j] = lo[j]; r[4 + j] = hi[j]; }
        *(short8*)&dst[(size_t)d * T_ + toff] = r;
    }
}

// ---------------- flash attention, S^T/O^T, in-register P^T, KT=128 ----------
// Block: 4 waves x 64 q = 256 q. Grid: 64 bh x 8 qtiles = 512 blocks.
// P^T never touches LDS: S^T C-layout packed reg pairs ARE the PV B-fragment
// dwords under a key permutation, and Vt's global layout bakes in the SAME
// permutation so the A-fragment is one b128 LDS read.
#define KLD 72    // Ks row stride (shorts), 144 B
#define VLD 136   // Vts row stride (shorts), 272 B

__global__ __launch_bounds__(256, 2) void attn_kernel(const unsigned short* __restrict__ Q,
                                                      const unsigned short* __restrict__ Kv,
                                                      const unsigned short* __restrict__ Vt,
                                                      unsigned short* __restrict__ Y) {
    __shared__ unsigned short smem[128 * KLD + 64 * VLD];   // 35840 B
    unsigned short* Ks = smem;                  // [key 0..127][d]
    unsigned short* Vts = smem + 128 * KLD;     // [d 0..63][key 0..127 perm]

    int bid = blockIdx.x;
    int qt = bid & 7;
    int bh = bid >> 3;
    int b = bh >> 4, hh = bh & 15;
    const unsigned short* qh = Q + (size_t)bh * T_ * DK_;
    const unsigned short* kh = Kv + (size_t)bh * T_ * DK_;
    const unsigned short* vtg = Vt + (size_t)bh * DK_ * T_;

    int tid = threadIdx.x, lane = tid & 63, w = tid >> 6;
    int l31 = lane & 31, h = lane >> 5;
    int qrA = qt * 256 + w * 32;
    int qrB = qrA + 128;

    // Q B-fragments held in registers: B[k=d][n=q], lane n=l31, k=16c+8h+j
    short8 qfA[4], qfB[4];
    for (int c = 0; c < 4; ++c) {
        qfA[c] = *(const short8*)&qh[(size_t)(qrA + l31) * DK_ + 16 * c + 8 * h];
        qfB[c] = *(const short8*)&qh[(size_t)(qrB + l31) * DK_ + 16 * c + 8 * h];
    }

    floatx16 oA0 = {}, oA1 = {}, oB0 = {}, oB1 = {};
    floatx2 lAv = {0.f, 0.f}, lBv = {0.f, 0.f};

    for (int kt = 0; kt < T_; kt += 128) {
        __syncthreads();
        // stage K [128 key][64 d] and Vt [64 d][128 key-perm]
        for (int it = 0; it < 4; ++it) {
            int idx = tid + it * 256;
            int r8 = idx >> 3, c8 = (idx & 7) * 8;
            *(short8*)&Ks[r8 * KLD + c8] = *(const short8*)&kh[(size_t)(kt + r8) * DK_ + c8];
            int vr = idx >> 4, vc = (idx & 15) * 8;
            *(short8*)&Vts[vr * VLD + vc] = *(const short8*)&vtg[(size_t)vr * T_ + kt + vc];
        }
        __syncthreads();

        for (int kk = 0; kk < 128; kk += 64) {
            // S^T = K . Q^T for both q-tiles; K-fragments shared
            floatx16 sA0 = {}, sA1 = {}, sB0 = {}, sB1 = {};
            for (int c = 0; c < 4; ++c) {
                short8 kf0 = *(const short8*)&Ks[(kk + l31) * KLD + 16 * c + 8 * h];
                short8 kf1 = *(const short8*)&Ks[(kk + 32 + l31) * KLD + 16 * c + 8 * h];
                sA0 = __builtin_amdgcn_mfma_f32_32x32x16_bf16(kf0, qfA[c], sA0, 0, 0, 0);
                sA1 = __builtin_amdgcn_mfma_f32_32x32x16_bf16(kf1, qfA[c], sA1, 0, 0, 0);
                sB0 = __builtin_amdgcn_mfma_f32_32x32x16_bf16(kf0, qfB[c], sB0, 0, 0, 0);
                sB1 = __builtin_amdgcn_mfma_f32_32x32x16_bf16(kf1, qfB[c], sB1, 0, 0, 0);
            }

            // exp2 (no max subtraction) + pack reg pairs -> PV B-frag dwords
            unsigned pA[16], pB[16];
            for (int r2 = 0; r2 < 8; ++r2) {
                float a0 = __builtin_amdgcn_exp2f(sA0[2 * r2]);
                float a1 = __builtin_amdgcn_exp2f(sA0[2 * r2 + 1]);
                pA[r2] = pack_bf16(a0, a1); lAv += (floatx2){a0, a1};
                float a2 = __builtin_amdgcn_exp2f(sA1[2 * r2]);
                float a3 = __builtin_amdgcn_exp2f(sA1[2 * r2 + 1]);
                pA[8 + r2] = pack_bf16(a2, a3); lAv += (floatx2){a2, a3};
                float b0 = __builtin_amdgcn_exp2f(sB0[2 * r2]);
                float b1 = __builtin_amdgcn_exp2f(sB0[2 * r2 + 1]);
                pB[r2] = pack_bf16(b0, b1); lBv += (floatx2){b0, b1};
                float b2 = __builtin_amdgcn_exp2f(sB1[2 * r2]);
                float b3 = __builtin_amdgcn_exp2f(sB1[2 * r2 + 1]);
                pB[8 + r2] = pack_bf16(b2, b3); lBv += (floatx2){b2, b3};
            }

            // O^T += V^T . P^T ; A-fragment = single b128 (layout pre-permuted)
            for (int c = 0; c < 4; ++c) {
                short8 vf0 = *(const short8*)&Vts[l31 * VLD + kk + 16 * c + 8 * h];
                short8 vf1 = *(const short8*)&Vts[(32 + l31) * VLD + kk + 16 * c + 8 * h];
                union { unsigned u[4]; short8 s; } fA, fB;
                for (int j = 0; j < 4; ++j) { fA.u[j] = pA[4 * c + j]; fB.u[j] = pB[4 * c + j]; }
                oA0 = __builtin_amdgcn_mfma_f32_32x32x16_bf16(vf0, fA.s, oA0, 0, 0, 0);
                oA1 = __builtin_amdgcn_mfma_f32_32x32x16_bf16(vf1, fA.s, oA1, 0, 0, 0);
                oB0 = __builtin_amdgcn_mfma_f32_32x32x16_bf16(vf0, fB.s, oB0, 0, 0, 0);
                oB1 = __builtin_amdgcn_mfma_f32_32x32x16_bf16(vf1, fB.s, oB1, 0, 0, 0);
            }
        }
    }

    // finalize l across key-halves; normalize; 2 passes through reused smem
    float lA = lAv.x + lAv.y, lB = lBv.x + lBv.y;
    float invA = 1.0f / (lA + __shfl_xor(lA, 32, 64));
    float invB = 1.0f / (lB + __shfl_xor(lB, 32, 64));
    int q_l = tid >> 1, seg = tid & 1;

    __syncthreads();
    for (int a = 0; a < 4; ++a) {
        ushort4 u;
        u.x = f2bf(oA0[4 * a + 0] * invA); u.y = f2bf(oA0[4 * a + 1] * invA);
        u.z = f2bf(oA0[4 * a + 2] * invA); u.w = f2bf(oA0[4 * a + 3] * invA);
        *(ushort4*)&smem[(w * 32 + l31) * KLD + 8 * a + 4 * h] = u;
        ushort4 v;
        v.x = f2bf(oA1[4 * a + 0] * invA); v.y = f2bf(oA1[4 * a + 1] * invA);
        v.z = f2bf(oA1[4 * a + 2] * invA); v.w = f2bf(oA1[4 * a + 3] * invA);
        *(ushort4*)&smem[(w * 32 + l31) * KLD + 32 + 8 * a + 4 * h] = v;
    }
    __syncthreads();
    {
        const unsigned short* srcp = &smem[(size_t)q_l * KLD + seg * 32];
        unsigned short* dstp = &Y[((size_t)b * T_ + qt * 256 + q_l) * C_ + hh * DK_ + seg * 32];
        for (int j = 0; j < 4; ++j)
            *(short8*)&dstp[8 * j] = *(const short8*)&srcp[8 * j];
    }
    __syncthreads();
    for (int a = 0; a < 4; ++a) {
        ushort4 u;
        u.x = f2bf(oB0[4 * a + 0] * invB); u.y = f2bf(oB0[4 * a + 1] * invB);
        u.z = f2bf(oB0[4 * a + 2] * invB); u.w = f2bf(oB0[4 * a + 3] * invB);
        *(ushort4*)&smem[(w * 32 + l31) * KLD + 8 * a + 4 * h] = u;
        ushort4 v;
        v.x = f2bf(oB1[4 * a + 0] * invB); v.y = f2bf(oB1[4 * a + 1] * invB);
        v.z = f2bf(oB1[4 * a + 2] * invB); v.w = f2bf(oB1[4 * a + 3] * invB);
        *(ushort4*)&smem[(w * 32 + l31) * KLD + 32 + 8 * a + 4 * h] = v;
    }
    __syncthreads();
    {
        const unsigned short* srcp = &smem[(size_t)q_l * KLD + seg * 32];
        unsigned short* dstp = &Y[((size_t)b * T_ + qt * 256 + 128 + q_l) * C_ + hh * DK_ + seg * 32];
        for (int j = 0; j < 4; ++j)
            *(short8*)&dstp[8 * j] = *(const short8*)&srcp[8 * j];
    }
}

extern "C" void kernel_launch(void* const* d_in, const int* in_sizes, int n_in,
                              void* d_out, int out_size, void* d_ws, size_t ws_size,
                              hipStream_t stream) {
    const float* x      = (const float*)d_in[0];
    const float* w_attn = (const float*)d_in[1];
    const float* b_attn = (const float*)d_in[2];
    const float* w_proj = (const float*)d_in[3];
    const float* b_proj = (const float*)d_in[4];
    float* out = (float*)d_out;

    unsigned short* ws = (unsigned short*)d_ws;
    unsigned short* xb  = ws;                       // 8192*1024 (reused as vtb)
    unsigned short* wab = xb  + (size_t)M_ * C_;    // 3072*1024
    unsigned short* wpb = wab + (size_t)N3_ * C_;   // 1024*1024
    unsigned short* qb  = wpb + (size_t)C_ * C_;    // [B,H,T,dk]
    unsigned short* kb  = qb  + (size_t)M_ * C_;    // [B,H,T,dk]
    unsigned short* vb  = kb  + (size_t)M_ * C_;    // [B,H,T,dk] natural
    unsigned short* yb  = vb  + (size_t)M_ * C_;    // 8192*1024
    unsigned short* vtb = xb;                       // [B,H,dk,T_perm] aliases xb

    cast3_kernel<<<(NX4 + NA4 + NP4) / 256, 256, 0, stream>>>(x, w_attn, w_proj, xb, wab, wpb);
    gemm_qkv<<<dim3(N3_ / BN, M_ / BM), 256, 0, stream>>>(xb, wab, b_attn, qb, kb, vb);
    vtrans_kernel<<<B_ * H_ * (T_ / 256), 256, 0, stream>>>(vb, vtb);
    attn_kernel<<<B_ * H_ * (T_ / 256), 256, 0, stream>>>(qb, kb, vtb, yb);
    gemm_proj<<<dim3(C_ / BN, M_ / BM), 256, 0, stream>>>(yb, wpb, b_proj, out);
}

// Round 7
// 273.350 us; speedup vs baseline: 1.1145x; 1.1145x over previous
//
#include <hip/hip_runtime.h>
#include <hip/hip_bf16.h>

typedef __attribute__((ext_vector_type(8))) short short8;
typedef __attribute__((ext_vector_type(4))) short short4v;
typedef __attribute__((ext_vector_type(4))) float floatx4;
typedef __attribute__((ext_vector_type(16))) float floatx16;

#define B_ 4
#define T_ 2048
#define C_ 1024
#define H_ 16
#define DK_ 64
#define M_ (B_ * T_)   // 8192
#define N3_ (3 * C_)   // 3072

// scale(1/8) * log2(e): folds softmax scaling AND exp->exp2 conversion into Q
#define QSCALE 0.1803368801111243f

__device__ __forceinline__ unsigned short f2bf(float f) {
    union { float f; unsigned u; } v; v.f = f;
    unsigned r = v.u + 0x7fffu + ((v.u >> 16) & 1u);
    return (unsigned short)(r >> 16);
}
__device__ __forceinline__ unsigned fbits(float f) {
    union { float f; unsigned u; } v; v.f = f; return v.u;
}
// pack two f32 -> dword of two bf16 (lo = a, hi = b)
__device__ __forceinline__ unsigned pack_bf16(float a, float b) {
#if __has_builtin(__builtin_amdgcn_cvt_pk_bf16_f32)
    typedef __attribute__((ext_vector_type(2))) __bf16 bf16x2;
    bf16x2 r = __builtin_amdgcn_cvt_pk_bf16_f32(a, b);
    union { bf16x2 v; unsigned u; } c; c.v = r; return c.u;
#else
    return __builtin_amdgcn_perm(fbits(b) + 0x8000u, fbits(a) + 0x8000u, 0x07060302u);
#endif
}

__device__ __forceinline__ void gload_lds16(const unsigned short* g, unsigned short* l) {
    __builtin_amdgcn_global_load_lds(
        (const __attribute__((address_space(1))) unsigned int*)(const void*)g,
        (__attribute__((address_space(3))) unsigned int*)(void*)l, 16, 0, 0);
}

// ---------------- fused cast fp32 -> bf16 for x, w_attn, w_proj --------------
#define NX4 (M_ * C_ / 4)     // 2097152
#define NA4 (N3_ * C_ / 4)    //  786432
#define NP4 (C_ * C_ / 4)     //  262144
__global__ __launch_bounds__(256) void cast3_kernel(const float* __restrict__ x,
                                                    const float* __restrict__ wa,
                                                    const float* __restrict__ wp,
                                                    unsigned short* __restrict__ xb,
                                                    unsigned short* __restrict__ wab,
                                                    unsigned short* __restrict__ wpb) {
    int i = blockIdx.x * 256 + threadIdx.x;
    const float* src; unsigned short* dst; int j;
    if (i < NX4) { src = x; dst = xb; j = i; }
    else if (i < NX4 + NA4) { src = wa; dst = wab; j = i - NX4; }
    else { src = wp; dst = wpb; j = i - NX4 - NA4; }
    float4 v = ((const float4*)src)[j];
    ushort4 o;
    o.x = f2bf(v.x); o.y = f2bf(v.y); o.z = f2bf(v.z); o.w = f2bf(v.w);
    ((ushort4*)dst)[j] = o;
}

// ---------------- B^T GEMM (m97 structure): out[m,n] = sum_k A[m,k]*W[n,k] ----
// BK=32 (BK=64 measured -20 µs regression in round 6 — keep 32).
#define BM 128
#define BN 128
#define BK 32

__global__ __launch_bounds__(256) void gemm_qkv(const unsigned short* __restrict__ A,
                                                const unsigned short* __restrict__ W,
                                                const float* __restrict__ bias,
                                                unsigned short* __restrict__ qout,
                                                unsigned short* __restrict__ kout,
                                                unsigned short* __restrict__ vout) {
    const int Kd = C_;
    __shared__ unsigned short As[BM * BK];
    __shared__ unsigned short Bs[BN * BK];
    int m0 = blockIdx.y * BM;
    int n0 = blockIdx.x * BN;
    int tid = threadIdx.x;
    int lane = tid & 63, w = tid >> 6;
    int wm = (w >> 1) * 64, wn = (w & 1) * 64;
    int l16 = lane & 15, quad = lane >> 4;
    int r4 = lane >> 2, c4 = (lane & 3) * 8;

    floatx4 acc[4][4] = {};
    for (int kt = 0; kt < Kd; kt += BK) {
        __syncthreads();
        for (int t = 0; t < 2; ++t) {
            int rbase = w * 32 + t * 16;
            gload_lds16(&A[(size_t)(m0 + rbase + r4) * Kd + kt + c4], &As[rbase * BK]);
            gload_lds16(&W[(size_t)(n0 + rbase + r4) * Kd + kt + c4], &Bs[rbase * BK]);
        }
        __syncthreads();
        short8 af[4], bf[4];
        for (int i = 0; i < 4; ++i)
            af[i] = *(const short8*)&As[(wm + 16 * i + l16) * BK + quad * 8];
        for (int j = 0; j < 4; ++j)
            bf[j] = *(const short8*)&Bs[(wn + 16 * j + l16) * BK + quad * 8];
        for (int i = 0; i < 4; ++i)
            for (int j = 0; j < 4; ++j)
                acc[i][j] = __builtin_amdgcn_mfma_f32_16x16x32_bf16(af[i], bf[j], acc[i][j], 0, 0, 0);
    }
    for (int i = 0; i < 4; ++i)
        for (int j = 0; j < 4; ++j) {
            int col = n0 + wn + 16 * j + l16;
            float bval = bias[col];
            int sec = col >> 10, cc = col & 1023;
            int h = cc >> 6, d = cc & 63;
            float qs = (sec == 0) ? QSCALE : 1.0f;
            unsigned short* dst = (sec == 0) ? qout : ((sec == 1) ? kout : vout);
            for (int r = 0; r < 4; ++r) {
                int m = m0 + wm + 16 * i + quad * 4 + r;
                int b = m >> 11, t = m & (T_ - 1);
                int bh = b * H_ + h;
                dst[((size_t)bh * T_ + t) * DK_ + d] = f2bf((acc[i][j][r] + bval) * qs);
            }
        }
}

__global__ __launch_bounds__(256) void gemm_proj(const unsigned short* __restrict__ A,
                                                 const unsigned short* __restrict__ W,
                                                 const float* __restrict__ bias,
                                                 float* __restrict__ out) {
    const int Kd = C_;
    __shared__ unsigned short As[BM * BK];
    __shared__ unsigned short Bs[BN * BK];
    int m0 = blockIdx.y * BM;
    int n0 = blockIdx.x * BN;
    int tid = threadIdx.x;
    int lane = tid & 63, w = tid >> 6;
    int wm = (w >> 1) * 64, wn = (w & 1) * 64;
    int l16 = lane & 15, quad = lane >> 4;
    int r4 = lane >> 2, c4 = (lane & 3) * 8;

    floatx4 acc[4][4] = {};
    for (int kt = 0; kt < Kd; kt += BK) {
        __syncthreads();
        for (int t = 0; t < 2; ++t) {
            int rbase = w * 32 + t * 16;
            gload_lds16(&A[(size_t)(m0 + rbase + r4) * Kd + kt + c4], &As[rbase * BK]);
            gload_lds16(&W[(size_t)(n0 + rbase + r4) * Kd + kt + c4], &Bs[rbase * BK]);
        }
        __syncthreads();
        short8 af[4], bf[4];
        for (int i = 0; i < 4; ++i)
            af[i] = *(const short8*)&As[(wm + 16 * i + l16) * BK + quad * 8];
        for (int j = 0; j < 4; ++j)
            bf[j] = *(const short8*)&Bs[(wn + 16 * j + l16) * BK + quad * 8];
        for (int i = 0; i < 4; ++i)
            for (int j = 0; j < 4; ++j)
                acc[i][j] = __builtin_amdgcn_mfma_f32_16x16x32_bf16(af[i], bf[j], acc[i][j], 0, 0, 0);
    }
    for (int i = 0; i < 4; ++i)
        for (int j = 0; j < 4; ++j) {
            int col = n0 + wn + 16 * j + l16;
            float bval = bias[col];
            for (int r = 0; r < 4; ++r) {
                int m = m0 + wm + 16 * i + quad * 4 + r;
                out[(size_t)m * C_ + col] = acc[i][j][r] + bval;
            }
        }
}

// ---------------- V transpose + key-permute: [bh,t,d] -> [bh,d,t_perm] -------
// Within each 16-key group, stored order is [0-3, 8-11, 4-7, 12-15]
// (p = (k&3)|((k&8)>>1)|((k&4)<<1)), so the attention PV A-fragment
// (keys {16c+4h..+3} u {16c+8+4h..+3}) is ONE contiguous b128 in LDS.
// Verified by counters: attn SQ_LDS_BANK_CONFLICT 4.39e6 -> 1.97e5.
#define TLD 264
__global__ __launch_bounds__(256) void vtrans_kernel(const unsigned short* __restrict__ V,
                                                     unsigned short* __restrict__ Vt) {
    __shared__ unsigned short L[64 * TLD];
    int bid = blockIdx.x;
    int t0 = (bid & 7) * 256;
    int bh = bid >> 3;
    int tid = threadIdx.x;
    const unsigned short* src = V + ((size_t)bh * T_ + t0) * DK_;
    unsigned short* dst = Vt + (size_t)bh * DK_ * T_ + t0;
    for (int it = 0; it < 8; ++it) {
        int t = it * 32 + (tid >> 3);
        int dseg = (tid & 7) * 8;
        short8 v = *(const short8*)&src[(size_t)t * DK_ + dseg];
        for (int j = 0; j < 8; ++j)
            L[(dseg + j) * TLD + t] = ((unsigned short*)&v)[j];
    }
    __syncthreads();
    for (int it = 0; it < 8; ++it) {
        int d = it * 8 + (tid >> 5);
        int toff = (tid & 31) * 8;
        int g = toff >> 4, s = (toff >> 3) & 1;
        short4v lo = *(const short4v*)&L[d * TLD + 16 * g + 4 * s];
        short4v hi = *(const short4v*)&L[d * TLD + 16 * g + 8 + 4 * s];
        short8 r;
        for (int j = 0; j < 4; ++j) { r[j] = lo[j]; r[4 + j] = hi[j]; }
        *(short8*)&dst[(size_t)d * T_ + toff] = r;
    }
}

// ---------------- flash attention, S^T/O^T, in-register P^T, KT=64 -----------
// Round-5 structure (measured best) + permuted-Vt single-b128 A-fragment.
// KT=128 measured -14 µs regression (round 6) — keep 64.
#define KT 64
#define LD 72   // LDS row stride (shorts): 144 B

__global__ __launch_bounds__(256, 2) void attn_kernel(const unsigned short* __restrict__ Q,
                                                      const unsigned short* __restrict__ Kv,
                                                      const unsigned short* __restrict__ Vt,
                                                      unsigned short* __restrict__ Y) {
    __shared__ unsigned short smem[128 * LD];   // rows 0..63 = Ks, 64..127 = Vts
    unsigned short* Ks = smem;                  // [key][d]
    unsigned short* Vts = smem + 64 * LD;       // [d][key-perm]

    int bid = blockIdx.x;
    int qt = bid & 7;
    int bh = bid >> 3;
    int b = bh >> 4, hh = bh & 15;
    const unsigned short* qh = Q + (size_t)bh * T_ * DK_;
    const unsigned short* kh = Kv + (size_t)bh * T_ * DK_;
    const unsigned short* vtg = Vt + (size_t)bh * DK_ * T_;

    int tid = threadIdx.x, lane = tid & 63, w = tid >> 6;
    int l31 = lane & 31, h = lane >> 5;
    int qrA = qt * 256 + w * 32;
    int qrB = qrA + 128;

    // Q B-fragments held in registers: B[k=d][n=q], lane n=l31, k=16c+8h+j
    short8 qfA[4], qfB[4];
    for (int c = 0; c < 4; ++c) {
        qfA[c] = *(const short8*)&qh[(size_t)(qrA + l31) * DK_ + 16 * c + 8 * h];
        qfB[c] = *(const short8*)&qh[(size_t)(qrB + l31) * DK_ + 16 * c + 8 * h];
    }

    floatx16 oA0 = {}, oA1 = {}, oB0 = {}, oB1 = {};
    float lA = 0.f, lB = 0.f;

    for (int kt = 0; kt < T_; kt += KT) {
        __syncthreads();
        for (int it = 0; it < 2; ++it) {
            int idx = tid + it * 256;
            int r8 = idx >> 3, c8 = (idx & 7) * 8;
            *(short8*)&Ks[r8 * LD + c8] = *(const short8*)&kh[(size_t)(kt + r8) * DK_ + c8];
            *(short8*)&Vts[r8 * LD + c8] = *(const short8*)&vtg[(size_t)r8 * T_ + kt + c8];
        }
        __syncthreads();

        // S^T = K . Q^T for both q-tiles; K-fragments shared
        floatx16 sA0 = {}, sA1 = {}, sB0 = {}, sB1 = {};
        for (int c = 0; c < 4; ++c) {
            short8 kf0 = *(const short8*)&Ks[l31 * LD + 16 * c + 8 * h];
            short8 kf1 = *(const short8*)&Ks[(32 + l31) * LD + 16 * c + 8 * h];
            sA0 = __builtin_amdgcn_mfma_f32_32x32x16_bf16(kf0, qfA[c], sA0, 0, 0, 0);
            sA1 = __builtin_amdgcn_mfma_f32_32x32x16_bf16(kf1, qfA[c], sA1, 0, 0, 0);
            sB0 = __builtin_amdgcn_mfma_f32_32x32x16_bf16(kf0, qfB[c], sB0, 0, 0, 0);
            sB1 = __builtin_amdgcn_mfma_f32_32x32x16_bf16(kf1, qfB[c], sB1, 0, 0, 0);
        }

        // exp2 (no max subtraction) + pack reg pairs -> PV B-frag dwords
        unsigned pA[16], pB[16];
        float tsA = 0.f, tsB = 0.f;
        for (int r2 = 0; r2 < 8; ++r2) {
            float a0 = __builtin_amdgcn_exp2f(sA0[2 * r2]);
            float a1 = __builtin_amdgcn_exp2f(sA0[2 * r2 + 1]);
            tsA += a0 + a1; pA[r2] = pack_bf16(a0, a1);
            float a2 = __builtin_amdgcn_exp2f(sA1[2 * r2]);
            float a3 = __builtin_amdgcn_exp2f(sA1[2 * r2 + 1]);
            tsA += a2 + a3; pA[8 + r2] = pack_bf16(a2, a3);
            float b0 = __builtin_amdgcn_exp2f(sB0[2 * r2]);
            float b1 = __builtin_amdgcn_exp2f(sB0[2 * r2 + 1]);
            tsB += b0 + b1; pB[r2] = pack_bf16(b0, b1);
            float b2 = __builtin_amdgcn_exp2f(sB1[2 * r2]);
            float b3 = __builtin_amdgcn_exp2f(sB1[2 * r2 + 1]);
            tsB += b2 + b3; pB[8 + r2] = pack_bf16(b2, b3);
        }
        lA += tsA; lB += tsB;

        // O^T += V^T . P^T ; A-fragment = single b128 (layout pre-permuted)
        for (int c = 0; c < 4; ++c) {
            short8 vf0 = *(const short8*)&Vts[l31 * LD + 16 * c + 8 * h];
            short8 vf1 = *(const short8*)&Vts[(32 + l31) * LD + 16 * c + 8 * h];
            union { unsigned u[4]; short8 s; } fA, fB;
            for (int j = 0; j < 4; ++j) { fA.u[j] = pA[4 * c + j]; fB.u[j] = pB[4 * c + j]; }
            oA0 = __builtin_amdgcn_mfma_f32_32x32x16_bf16(vf0, fA.s, oA0, 0, 0, 0);
            oA1 = __builtin_amdgcn_mfma_f32_32x32x16_bf16(vf1, fA.s, oA1, 0, 0, 0);
            oB0 = __builtin_amdgcn_mfma_f32_32x32x16_bf16(vf0, fB.s, oB0, 0, 0, 0);
            oB1 = __builtin_amdgcn_mfma_f32_32x32x16_bf16(vf1, fB.s, oB1, 0, 0, 0);
        }
    }

    // finalize l across key-halves; normalize; 2 passes through reused smem
    float invA = 1.0f / (lA + __shfl_xor(lA, 32, 64));
    float invB = 1.0f / (lB + __shfl_xor(lB, 32, 64));
    int q_l = tid >> 1, seg = tid & 1;

    __syncthreads();
    for (int a = 0; a < 4; ++a) {
        ushort4 u;
        u.x = f2bf(oA0[4 * a + 0] * invA); u.y = f2bf(oA0[4 * a + 1] * invA);
        u.z = f2bf(oA0[4 * a + 2] * invA); u.w = f2bf(oA0[4 * a + 3] * invA);
        *(ushort4*)&smem[(w * 32 + l31) * LD + 8 * a + 4 * h] = u;
        ushort4 v;
        v.x = f2bf(oA1[4 * a + 0] * invA); v.y = f2bf(oA1[4 * a + 1] * invA);
        v.z = f2bf(oA1[4 * a + 2] * invA); v.w = f2bf(oA1[4 * a + 3] * invA);
        *(ushort4*)&smem[(w * 32 + l31) * LD + 32 + 8 * a + 4 * h] = v;
    }
    __syncthreads();
    {
        const unsigned short* srcp = &smem[(size_t)q_l * LD + seg * 32];
        unsigned short* dstp = &Y[((size_t)b * T_ + qt * 256 + q_l) * C_ + hh * DK_ + seg * 32];
        for (int j = 0; j < 4; ++j)
            *(short8*)&dstp[8 * j] = *(const short8*)&srcp[8 * j];
    }
    __syncthreads();
    for (int a = 0; a < 4; ++a) {
        ushort4 u;
        u.x = f2bf(oB0[4 * a + 0] * invB); u.y = f2bf(oB0[4 * a + 1] * invB);
        u.z = f2bf(oB0[4 * a + 2] * invB); u.w = f2bf(oB0[4 * a + 3] * invB);
        *(ushort4*)&smem[(w * 32 + l31) * LD + 8 * a + 4 * h] = u;
        ushort4 v;
        v.x = f2bf(oB1[4 * a + 0] * invB); v.y = f2bf(oB1[4 * a + 1] * invB);
        v.z = f2bf(oB1[4 * a + 2] * invB); v.w = f2bf(oB1[4 * a + 3] * invB);
        *(ushort4*)&smem[(w * 32 + l31) * LD + 32 + 8 * a + 4 * h] = v;
    }
    __syncthreads();
    {
        const unsigned short* srcp = &smem[(size_t)q_l * LD + seg * 32];
        unsigned short* dstp = &Y[((size_t)b * T_ + qt * 256 + 128 + q_l) * C_ + hh * DK_ + seg * 32];
        for (int j = 0; j < 4; ++j)
            *(short8*)&dstp[8 * j] = *(const short8*)&srcp[8 * j];
    }
}

extern "C" void kernel_launch(void* const* d_in, const int* in_sizes, int n_in,
                              void* d_out, int out_size, void* d_ws, size_t ws_size,
                              hipStream_t stream) {
    const float* x      = (const float*)d_in[0];
    const float* w_attn = (const float*)d_in[1];
    const float* b_attn = (const float*)d_in[2];
    const float* w_proj = (const float*)d_in[3];
    const float* b_proj = (const float*)d_in[4];
    float* out = (float*)d_out;

    unsigned short* ws = (unsigned short*)d_ws;
    unsigned short* xb  = ws;                       // 8192*1024 (reused as vtb)
    unsigned short* wab = xb  + (size_t)M_ * C_;    // 3072*1024
    unsigned short* wpb = wab + (size_t)N3_ * C_;   // 1024*1024
    unsigned short* qb  = wpb + (size_t)C_ * C_;    // [B,H,T,dk]
    unsigned short* kb  = qb  + (size_t)M_ * C_;    // [B,H,T,dk]
    unsigned short* vb  = kb  + (size_t)M_ * C_;    // [B,H,T,dk] natural
    unsigned short* yb  = vb  + (size_t)M_ * C_;    // 8192*1024
    unsigned short* vtb = xb;                       // [B,H,dk,T_perm] aliases xb

    cast3_kernel<<<(NX4 + NA4 + NP4) / 256, 256, 0, stream>>>(x, w_attn, w_proj, xb, wab, wpb);
    gemm_qkv<<<dim3(N3_ / BN, M_ / BM), 256, 0, stream>>>(xb, wab, b_attn, qb, kb, vb);
    vtrans_kernel<<<B_ * H_ * (T_ / 256), 256, 0, stream>>>(vb, vtb);
    attn_kernel<<<B_ * H_ * (T_ / 256), 256, 0, stream>>>(qb, kb, vtb, yb);
    gemm_proj<<<dim3(C_ / BN, M_ / BM), 256, 0, stream>>>(yb, wpb, b_proj, out);
}